// Round 1
// baseline (1946.541 us; speedup 1.0000x reference)
//
#include <hip/hip_runtime.h>

#define N_NODES 50000
#define N_EDGES 800000
#define MUL0 64
#define MUL1 32
#define D_IN 160      // 64 + 3*32
#define FC_H 64
#define W_NUMEL 192   // 64+64+32+32
#define FEAT 384      // per-node accumulated edge features: 64 + 32 + 192 + 96
#define ACT_C 1.6791f
#define INV_SQRT3 0.57735026918962576f
#define RSQRT32 0.17677669529663687f
#define RSQRT96 0.10206207261596575f

#define TILE 32       // edges per block

__global__ __launch_bounds__(256) void zero_kernel(float* p, size_t n) {
    size_t i = (size_t)blockIdx.x * blockDim.x + threadIdx.x;
    size_t stride = (size_t)gridDim.x * blockDim.x;
    for (; i < n; i += stride) p[i] = 0.f;
}

// Fused: edge MLP (2 layers) + tensor-product edge features + atomic segment-sum
__global__ __launch_bounds__(256) void edge_kernel(
    const float* __restrict__ x,         // N x 160
    const float* __restrict__ es,        // E x 64
    const float* __restrict__ sh,        // E x 4
    const int*   __restrict__ eidx,      // 2 x E
    const float* __restrict__ w_fc1,     // 64 x 64
    const float* __restrict__ w_fc2,     // 64 x 192
    float* __restrict__ accg,            // N x 384
    float* __restrict__ cntg)            // N
{
    __shared__ float s_es[TILE][FC_H];   // edge_scalars tile; reused to hold h
    __shared__ float s_w[TILE][W_NUMEL]; // weight tile
    __shared__ float s_x[TILE][D_IN];    // gathered x[src] rows
    __shared__ float s_sh[TILE][4];
    __shared__ int   s_src[TILE];
    __shared__ int   s_dst[TILE];

    const int t = threadIdx.x;
    const int tile0 = blockIdx.x * TILE;

    // ---- stage edge_scalars (contiguous 8KB), sh, indices ----
    {
        const float* esb = es + (size_t)tile0 * FC_H;
        for (int i = t; i < TILE * FC_H; i += 256) (&s_es[0][0])[i] = esb[i];
        for (int i = t; i < TILE * 4; i += 256) (&s_sh[0][0])[i] = sh[(size_t)tile0 * 4 + i];
        if (t < TILE) {
            s_src[t] = eidx[tile0 + t];
            s_dst[t] = eidx[N_EDGES + tile0 + t];
        }
    }
    __syncthreads();

    const int u = t & 63;    // output column
    const int g = t >> 6;    // edge-group 0..3 (8 edges each)

    // ---- layer 1: h = silu(es @ w_fc1 / 8) * ACT_C  (into registers) ----
    float hacc[8];
#pragma unroll
    for (int r = 0; r < 8; ++r) hacc[r] = 0.f;
    for (int k = 0; k < FC_H; ++k) {
        float w = w_fc1[k * FC_H + u];
#pragma unroll
        for (int r = 0; r < 8; ++r) hacc[r] += s_es[g * 8 + r][k] * w;
    }
#pragma unroll
    for (int r = 0; r < 8; ++r) {
        float a = hacc[r] * 0.125f;
        hacc[r] = a * (1.f / (1.f + __expf(-a))) * ACT_C;
    }

    // ---- gather x[src] rows into LDS (overlaps with MLP) ----
    for (int i = t; i < TILE * D_IN; i += 256) {
        int e = i / D_IN, f = i - e * D_IN;
        s_x[e][f] = x[(size_t)s_src[e] * D_IN + f];
    }
    __syncthreads();            // all reads of s_es done
#pragma unroll
    for (int r = 0; r < 8; ++r) s_es[g * 8 + r][u] = hacc[r];  // s_es now holds h
    __syncthreads();

    // ---- layer 2: weight = h @ w_fc2 / 8 ----
#pragma unroll
    for (int cb = 0; cb < 3; ++cb) {
        float acc[8];
#pragma unroll
        for (int r = 0; r < 8; ++r) acc[r] = 0.f;
        for (int k = 0; k < FC_H; ++k) {
            float w = w_fc2[k * W_NUMEL + cb * 64 + u];
#pragma unroll
            for (int r = 0; r < 8; ++r) acc[r] += s_es[g * 8 + r][k] * w;
        }
#pragma unroll
        for (int r = 0; r < 8; ++r) s_w[g * 8 + r][cb * 64 + u] = acc[r] * 0.125f;
    }
    __syncthreads();

    // ---- tensor-product features + atomic scatter ----
    // layout per node: [0:64) s0, [64:96) s1, [96:288) v0 (u*3+i), [288:384) v1 (u*3+i)
    for (int j = 0; j < 48; ++j) {      // 48*256 = 32*384
        int idx = t + j * 256;
        int e = idx / 384;
        int f = idx - e * 384;
        const float* W = s_w[e];
        const float* X = s_x[e];
        const float* S = s_sh[e];
        float val;
        if (f < 64) {
            val = W[f] * X[f] * S[0];
        } else if (f < 96) {
            int uu = f - 64;
            val = W[160 + uu] *
                  (X[64 + uu * 3] * S[1] + X[64 + uu * 3 + 1] * S[2] + X[64 + uu * 3 + 2] * S[3]) *
                  INV_SQRT3;
        } else if (f < 288) {
            int kk = f - 96;
            int uu = kk / 3;
            int ii = kk - uu * 3;
            val = W[64 + uu] * X[uu] * S[1 + ii];
        } else {
            int kk = f - 288;
            val = W[128 + kk / 3] * X[64 + kk] * S[0];
        }
        atomicAdd(&accg[(size_t)s_dst[e] * FEAT + f], val);
    }
    if (t < TILE) atomicAdd(&cntg[s_dst[t]], 1.f);
}

// Node epilogue: mean, alpha, self-connection + gate*linear
__global__ __launch_bounds__(256) void node_kernel(
    const float* __restrict__ x,
    const float* __restrict__ accg,
    const float* __restrict__ cntg,
    const float* __restrict__ w_sc_s,   // 64 x 64
    const float* __restrict__ w_sc_v,   // 32 x 32
    const float* __restrict__ w_lin_s,  // 96 x 64
    const float* __restrict__ w_lin_v,  // 96 x 32
    const float* __restrict__ w_alpha,  // 96
    float* __restrict__ out)            // N x 160
{
    __shared__ float s_m[16][FEAT];     // mean rows (24KB)
    __shared__ float s_x[16][D_IN];     // x rows (10KB)
    __shared__ float s_alpha[16];

    const int t = threadIdx.x;
    const int n0 = blockIdx.x * 16;

    for (int i = t; i < 16 * FEAT; i += 256) {
        int r = i / FEAT, f = i - r * FEAT;
        int n = n0 + r;
        float v = 0.f;
        if (n < N_NODES) {
            float c = fmaxf(cntg[n], 1.f);
            v = accg[(size_t)n * FEAT + f] / c;
        }
        s_m[r][f] = v;
    }
    for (int i = t; i < 16 * D_IN; i += 256) {
        int r = i / D_IN, f = i - r * D_IN;
        int n = n0 + r;
        s_x[r][f] = (n < N_NODES) ? x[(size_t)n * D_IN + f] : 0.f;
    }
    __syncthreads();

    if (t < 16) {
        float a = 0.f;
        for (int uu = 0; uu < 96; ++uu) a += s_m[t][uu] * w_alpha[uu];
        s_alpha[t] = a * RSQRT96;
    }
    __syncthreads();

    if (t < 160) {
        const int c = t;
        float scv[16], lin[16];
#pragma unroll
        for (int r = 0; r < 16; ++r) { scv[r] = 0.f; lin[r] = 0.f; }
        if (c < 64) {
            for (int uu = 0; uu < 64; ++uu) {
                float w = w_sc_s[uu * 64 + c];
#pragma unroll
                for (int r = 0; r < 16; ++r) scv[r] += s_x[r][uu] * w;
            }
            for (int uu = 0; uu < 96; ++uu) {
                float w = w_lin_s[uu * 64 + c];
#pragma unroll
                for (int r = 0; r < 16; ++r) lin[r] += s_m[r][uu] * w;
            }
#pragma unroll
            for (int r = 0; r < 16; ++r) {
                int n = n0 + r;
                if (n < N_NODES)
                    out[(size_t)n * 160 + c] = scv[r] * 0.125f + s_alpha[r] * lin[r] * RSQRT96;
            }
        } else {
            const int k = c - 64;
            const int wcol = k / 3;
            const int ii = k - wcol * 3;
            for (int uu = 0; uu < 32; ++uu) {
                float w = w_sc_v[uu * 32 + wcol];
#pragma unroll
                for (int r = 0; r < 16; ++r) scv[r] += s_x[r][64 + uu * 3 + ii] * w;
            }
            for (int uu = 0; uu < 96; ++uu) {
                float w = w_lin_v[uu * 32 + wcol];
#pragma unroll
                for (int r = 0; r < 16; ++r) lin[r] += s_m[r][96 + uu * 3 + ii] * w;
            }
#pragma unroll
            for (int r = 0; r < 16; ++r) {
                int n = n0 + r;
                if (n < N_NODES)
                    out[(size_t)n * 160 + c] = scv[r] * RSQRT32 + s_alpha[r] * lin[r] * RSQRT96;
            }
        }
    }
}

extern "C" void kernel_launch(void* const* d_in, const int* in_sizes, int n_in,
                              void* d_out, int out_size, void* d_ws, size_t ws_size,
                              hipStream_t stream) {
    const float* x        = (const float*)d_in[0];
    const float* es       = (const float*)d_in[1];
    const float* sh       = (const float*)d_in[2];
    const int*   eidx     = (const int*)d_in[3];
    const float* w_fc1    = (const float*)d_in[4];
    const float* w_fc2    = (const float*)d_in[5];
    const float* w_sc_s   = (const float*)d_in[6];
    const float* w_sc_v   = (const float*)d_in[7];
    const float* w_lin_s  = (const float*)d_in[8];
    const float* w_lin_v  = (const float*)d_in[9];
    const float* w_alpha  = (const float*)d_in[10];
    float* out = (float*)d_out;

    float* accg = (float*)d_ws;                       // N x 384
    float* cntg = accg + (size_t)N_NODES * FEAT;      // N
    size_t ztotal = (size_t)N_NODES * FEAT + N_NODES;

    hipLaunchKernelGGL(zero_kernel, dim3(2048), dim3(256), 0, stream, accg, ztotal);
    hipLaunchKernelGGL(edge_kernel, dim3(N_EDGES / TILE), dim3(256), 0, stream,
                       x, es, sh, eidx, w_fc1, w_fc2, accg, cntg);
    hipLaunchKernelGGL(node_kernel, dim3(N_NODES / 16), dim3(256), 0, stream,
                       x, accg, cntg, w_sc_s, w_sc_v, w_lin_s, w_lin_v, w_alpha, out);
}

// Round 2
// 1484.456 us; speedup vs baseline: 1.3113x; 1.3113x over previous
//
#include <hip/hip_runtime.h>

#define N_NODES 50000
#define N_EDGES 800000
#define MUL0 64
#define MUL1 32
#define D_IN 160      // 64 + 3*32
#define FC_H 64
#define W_NUMEL 192   // 64+64+32+32
#define FEAT 384      // 64 + 32 + 192 + 96
#define ACT_C 1.6791f
#define INV_SQRT3 0.57735026918962576f
#define RSQRT32 0.17677669529663687f
#define RSQRT96 0.10206207261596575f

#define TILE 32       // edges per block (sorted by dst)

// ---------------- utility kernels ----------------

__global__ __launch_bounds__(256) void zero_kernel(float* p, size_t n) {
    size_t i = (size_t)blockIdx.x * blockDim.x + threadIdx.x;
    size_t stride = (size_t)gridDim.x * blockDim.x;
    for (; i < n; i += stride) p[i] = 0.f;
}

__global__ __launch_bounds__(256) void hist_kernel(const int* __restrict__ eidx,
                                                   int* __restrict__ cnt) {
    int e = blockIdx.x * 256 + threadIdx.x;
    if (e < N_EDGES) atomicAdd(&cnt[eidx[N_EDGES + e]], 1);
}

__global__ __launch_bounds__(1024) void scan_kernel(const int* __restrict__ cnt,
                                                    int* __restrict__ offs,
                                                    int* __restrict__ fill) {
    __shared__ int s_part[1024];
    const int t = threadIdx.x;
    const int CH = (N_NODES + 1023) / 1024;   // 49
    int i0 = t * CH, i1 = min(i0 + CH, N_NODES);
    int s = 0;
    for (int i = i0; i < i1; ++i) s += cnt[i];
    s_part[t] = s;
    __syncthreads();
    if (t == 0) {
        int run = 0;
        for (int i = 0; i < 1024; ++i) { int v = s_part[i]; s_part[i] = run; run += v; }
    }
    __syncthreads();
    int run = s_part[t];
    for (int i = i0; i < i1; ++i) { offs[i] = run; fill[i] = run; run += cnt[i]; }
}

__global__ __launch_bounds__(256) void scatter_ids_kernel(const int* __restrict__ eidx,
                                                          int* __restrict__ fill,
                                                          int* __restrict__ sorted_eid) {
    int e = blockIdx.x * 256 + threadIdx.x;
    if (e < N_EDGES) {
        int p = atomicAdd(&fill[eidx[N_EDGES + e]], 1);
        sorted_eid[p] = e;
    }
}

// ---------------- fused edge kernel (sorted by dst) ----------------

__global__ __launch_bounds__(256) void edge_kernel(
    const float* __restrict__ x,          // N x 160
    const float* __restrict__ es,         // E x 64
    const float* __restrict__ sh,         // E x 4
    const int*   __restrict__ eidx,       // 2 x E
    const int*   __restrict__ sorted_eid, // E
    const float* __restrict__ w_fc1,      // 64 x 64
    const float* __restrict__ w_fc2,      // 64 x 192
    float* __restrict__ accg)             // N x 384
{
    __shared__ float s_es[TILE][FC_H];    // 8KB; holds es, then h
    __shared__ float s_w[TILE][W_NUMEL];  // 24KB
    __shared__ float s_x[TILE][D_IN];     // 20KB
    __shared__ float s_sh[TILE][4];
    __shared__ int   s_eid[TILE], s_src[TILE], s_dst[TILE], s_flush[TILE];

    const int t = threadIdx.x;
    const int tile0 = blockIdx.x * TILE;

    if (t < TILE) {
        int eid = sorted_eid[tile0 + t];
        s_eid[t] = eid;
        s_src[t] = eidx[eid];
        s_dst[t] = eidx[N_EDGES + eid];
    }
    __syncthreads();
    if (t < TILE) s_flush[t] = (t == TILE - 1) || (s_dst[t] != s_dst[t + 1]);
    for (int i = t; i < TILE * FC_H; i += 256) {
        int e = i >> 6, f = i & 63;
        s_es[e][f] = es[(size_t)s_eid[e] * FC_H + f];
    }
    for (int i = t; i < TILE * 4; i += 256) {
        int e = i >> 2, c4 = i & 3;
        s_sh[e][c4] = sh[(size_t)s_eid[e] * 4 + c4];
    }
    for (int i = t; i < TILE * D_IN; i += 256) {
        int e = i / D_IN, f = i - e * D_IN;
        s_x[e][f] = x[(size_t)s_src[e] * D_IN + f];
    }

    // phase-C per-thread feature precompute (hoisted out of hot loops)
    const int f0 = t;
    const int f1 = (t < 128) ? 256 + t : -1;
    int wi0, xi0, si0, mode0; float sc0;
    {
        int f = f0;
        if (f < 64)       { mode0 = 0; wi0 = f;                xi0 = f;          si0 = 0;              sc0 = 1.f; }
        else if (f < 96)  { int uu = f - 64; mode0 = 1; wi0 = 160 + uu; xi0 = 64 + 3 * uu; si0 = 0;    sc0 = INV_SQRT3; }
        else if (f < 288) { int kk = f - 96; int uu = kk / 3; mode0 = 0; wi0 = 64 + uu; xi0 = uu; si0 = 1 + (kk - 3 * uu); sc0 = 1.f; }
        else              { int kk = f - 288; mode0 = 0; wi0 = 128 + kk / 3; xi0 = 64 + kk; si0 = 0;   sc0 = 1.f; }
    }
    int wi1 = 0, xi1 = 0, si1 = 0;
    if (f1 >= 0) {   // f1 in [256,384): always mode 0
        if (f1 < 288) { int kk = f1 - 96; int uu = kk / 3; wi1 = 64 + uu; xi1 = uu; si1 = 1 + (kk - 3 * uu); }
        else          { int kk = f1 - 288; wi1 = 128 + kk / 3; xi1 = 64 + kk; si1 = 0; }
    }
    __syncthreads();

    const int c  = t & 63;    // output column
    const int eg = t >> 6;    // edge-group (8 edges each)

    // ---- layer 1: h = silu(es @ w_fc1 / 8) * ACT_C ----
    float acc1[8];
#pragma unroll
    for (int r = 0; r < 8; ++r) acc1[r] = 0.f;
    for (int kc = 0; kc < 16; ++kc) {
        float4 ef[8];
#pragma unroll
        for (int r = 0; r < 8; ++r) ef[r] = *(const float4*)&s_es[eg * 8 + r][kc * 4];
        float w0 = w_fc1[(kc * 4 + 0) * FC_H + c];
        float w1 = w_fc1[(kc * 4 + 1) * FC_H + c];
        float w2 = w_fc1[(kc * 4 + 2) * FC_H + c];
        float w3 = w_fc1[(kc * 4 + 3) * FC_H + c];
#pragma unroll
        for (int r = 0; r < 8; ++r)
            acc1[r] += ef[r].x * w0 + ef[r].y * w1 + ef[r].z * w2 + ef[r].w * w3;
    }
    float hval[8];
#pragma unroll
    for (int r = 0; r < 8; ++r) {
        float a = acc1[r] * 0.125f;
        hval[r] = a * (1.f / (1.f + __expf(-a))) * ACT_C;
    }
    __syncthreads();   // all layer-1 reads of s_es done
#pragma unroll
    for (int r = 0; r < 8; ++r) s_es[eg * 8 + r][c] = hval[r];
    __syncthreads();

    // ---- layer 2: weight = h @ w_fc2 / 8 (24 accumulators, h-frags shared) ----
    float acc2[3][8];
#pragma unroll
    for (int cb = 0; cb < 3; ++cb)
#pragma unroll
        for (int r = 0; r < 8; ++r) acc2[cb][r] = 0.f;
    for (int kc = 0; kc < 16; ++kc) {
        float4 hf[8];
#pragma unroll
        for (int r = 0; r < 8; ++r) hf[r] = *(const float4*)&s_es[eg * 8 + r][kc * 4];
        float wv[3][4];
#pragma unroll
        for (int cb = 0; cb < 3; ++cb)
#pragma unroll
            for (int q = 0; q < 4; ++q)
                wv[cb][q] = w_fc2[(kc * 4 + q) * W_NUMEL + cb * 64 + c];
#pragma unroll
        for (int cb = 0; cb < 3; ++cb)
#pragma unroll
            for (int r = 0; r < 8; ++r)
                acc2[cb][r] += hf[r].x * wv[cb][0] + hf[r].y * wv[cb][1] +
                               hf[r].z * wv[cb][2] + hf[r].w * wv[cb][3];
    }
#pragma unroll
    for (int cb = 0; cb < 3; ++cb)
#pragma unroll
        for (int r = 0; r < 8; ++r)
            s_w[eg * 8 + r][cb * 64 + c] = acc2[cb][r] * 0.125f;
    __syncthreads();

    // ---- phase C: segmented register accumulation + one atomic per segment ----
    float a0 = 0.f, a1 = 0.f;
#pragma unroll 4
    for (int e = 0; e < TILE; ++e) {
        {
            float W = s_w[e][wi0];
            float v;
            if (mode0) {
                v = W * (s_x[e][xi0]     * s_sh[e][1] +
                         s_x[e][xi0 + 1] * s_sh[e][2] +
                         s_x[e][xi0 + 2] * s_sh[e][3]);
            } else {
                v = W * s_x[e][xi0] * s_sh[e][si0];
            }
            a0 += v;
        }
        if (t < 128) {
            float W = s_w[e][wi1];
            a1 += W * s_x[e][xi1] * s_sh[e][si1];
        }
        if (s_flush[e]) {
            float* dstp = accg + (size_t)s_dst[e] * FEAT;
            atomicAdd(dstp + f0, a0 * sc0);
            a0 = 0.f;
            if (t < 128) { atomicAdd(dstp + f1, a1); a1 = 0.f; }
        }
    }
}

// ---------------- node epilogue ----------------

__global__ __launch_bounds__(256) void node_kernel(
    const float* __restrict__ x,
    const float* __restrict__ accg,
    const int*   __restrict__ cnt,
    const float* __restrict__ w_sc_s,   // 64 x 64
    const float* __restrict__ w_sc_v,   // 32 x 32
    const float* __restrict__ w_lin_s,  // 96 x 64
    const float* __restrict__ w_lin_v,  // 96 x 32
    const float* __restrict__ w_alpha,  // 96
    float* __restrict__ out)            // N x 160
{
    __shared__ float s_m[16][FEAT];
    __shared__ float s_x[16][D_IN];
    __shared__ float s_alpha[16];

    const int t = threadIdx.x;
    const int n0 = blockIdx.x * 16;

    for (int i = t; i < 16 * FEAT; i += 256) {
        int r = i / FEAT, f = i - r * FEAT;
        int n = n0 + r;
        float v = 0.f;
        if (n < N_NODES) {
            float cdiv = 1.f / (float)max(cnt[n], 1);
            v = accg[(size_t)n * FEAT + f] * cdiv;
        }
        s_m[r][f] = v;
    }
    for (int i = t; i < 16 * D_IN; i += 256) {
        int r = i / D_IN, f = i - r * D_IN;
        int n = n0 + r;
        s_x[r][f] = (n < N_NODES) ? x[(size_t)n * D_IN + f] : 0.f;
    }
    __syncthreads();

    if (t < 16) {
        float a = 0.f;
        for (int uu = 0; uu < 96; ++uu) a += s_m[t][uu] * w_alpha[uu];
        s_alpha[t] = a * RSQRT96;
    }
    __syncthreads();

    if (t < 160) {
        const int c = t;
        float scv[16], lin[16];
#pragma unroll
        for (int r = 0; r < 16; ++r) { scv[r] = 0.f; lin[r] = 0.f; }
        if (c < 64) {
            for (int uu = 0; uu < 64; ++uu) {
                float w = w_sc_s[uu * 64 + c];
#pragma unroll
                for (int r = 0; r < 16; ++r) scv[r] += s_x[r][uu] * w;
            }
            for (int uu = 0; uu < 96; ++uu) {
                float w = w_lin_s[uu * 64 + c];
#pragma unroll
                for (int r = 0; r < 16; ++r) lin[r] += s_m[r][uu] * w;
            }
#pragma unroll
            for (int r = 0; r < 16; ++r) {
                int n = n0 + r;
                if (n < N_NODES)
                    out[(size_t)n * 160 + c] = scv[r] * 0.125f + s_alpha[r] * lin[r] * RSQRT96;
            }
        } else {
            const int k = c - 64;
            const int wcol = k / 3;
            const int ii = k - wcol * 3;
            for (int uu = 0; uu < 32; ++uu) {
                float w = w_sc_v[uu * 32 + wcol];
#pragma unroll
                for (int r = 0; r < 16; ++r) scv[r] += s_x[r][64 + uu * 3 + ii] * w;
            }
            for (int uu = 0; uu < 96; ++uu) {
                float w = w_lin_v[uu * 32 + wcol];
#pragma unroll
                for (int r = 0; r < 16; ++r) lin[r] += s_m[r][96 + uu * 3 + ii] * w;
            }
#pragma unroll
            for (int r = 0; r < 16; ++r) {
                int n = n0 + r;
                if (n < N_NODES)
                    out[(size_t)n * 160 + c] = scv[r] * RSQRT32 + s_alpha[r] * lin[r] * RSQRT96;
            }
        }
    }
}

// ---------------- launch ----------------

extern "C" void kernel_launch(void* const* d_in, const int* in_sizes, int n_in,
                              void* d_out, int out_size, void* d_ws, size_t ws_size,
                              hipStream_t stream) {
    const float* x        = (const float*)d_in[0];
    const float* es       = (const float*)d_in[1];
    const float* sh       = (const float*)d_in[2];
    const int*   eidx     = (const int*)d_in[3];
    const float* w_fc1    = (const float*)d_in[4];
    const float* w_fc2    = (const float*)d_in[5];
    const float* w_sc_s   = (const float*)d_in[6];
    const float* w_sc_v   = (const float*)d_in[7];
    const float* w_lin_s  = (const float*)d_in[8];
    const float* w_lin_v  = (const float*)d_in[9];
    const float* w_alpha  = (const float*)d_in[10];
    float* out = (float*)d_out;

    // workspace layout (4-byte words)
    float* accg       = (float*)d_ws;                                  // N*384
    int*   cnt        = (int*)(accg + (size_t)N_NODES * FEAT);         // N
    int*   offs       = cnt + N_NODES;                                 // N
    int*   fill       = offs + N_NODES;                                // N
    int*   sorted_eid = fill + N_NODES;                                // E

    // zero accg + cnt in one pass (contiguous)
    hipLaunchKernelGGL(zero_kernel, dim3(2048), dim3(256), 0, stream,
                       accg, (size_t)N_NODES * (FEAT + 1));
    hipLaunchKernelGGL(hist_kernel, dim3((N_EDGES + 255) / 256), dim3(256), 0, stream,
                       eidx, cnt);
    hipLaunchKernelGGL(scan_kernel, dim3(1), dim3(1024), 0, stream, cnt, offs, fill);
    hipLaunchKernelGGL(scatter_ids_kernel, dim3((N_EDGES + 255) / 256), dim3(256), 0, stream,
                       eidx, fill, sorted_eid);
    hipLaunchKernelGGL(edge_kernel, dim3(N_EDGES / TILE), dim3(256), 0, stream,
                       x, es, sh, eidx, sorted_eid, w_fc1, w_fc2, accg);
    hipLaunchKernelGGL(node_kernel, dim3((N_NODES + 15) / 16), dim3(256), 0, stream,
                       x, accg, cnt, w_sc_s, w_sc_v, w_lin_s, w_lin_v, w_alpha, out);
}

// Round 3
// 1040.358 us; speedup vs baseline: 1.8710x; 1.4269x over previous
//
#include <hip/hip_runtime.h>

#define N_NODES 50000
#define N_EDGES 800000
#define MUL0 64
#define MUL1 32
#define D_IN 160      // 64 + 3*32
#define FC_H 64
#define W_NUMEL 192   // 64+64+32+32
#define FEAT 384      // 64 + 32 + 192 + 96
#define ACT_C 1.6791f
#define INV_SQRT3 0.57735026918962576f
#define RSQRT32 0.17677669529663687f
#define RSQRT96 0.10206207261596575f

#define TILE 64       // edges per block (sorted by dst)

typedef __attribute__((ext_vector_type(8))) short s16x8;
typedef __attribute__((ext_vector_type(4))) float f32x4;

static __device__ __forceinline__ unsigned short f2bf(float f) {
    unsigned u = __builtin_bit_cast(unsigned, f);
    unsigned r = (u + 0x7fffu + ((u >> 16) & 1u)) >> 16;   // RNE
    return (unsigned short)r;
}
static __device__ __forceinline__ float bf2f(unsigned short b) {
    return __builtin_bit_cast(float, (unsigned)b << 16);
}

// ---------------- utility kernels ----------------

__global__ __launch_bounds__(256) void zero_kernel(float* p, size_t n) {
    size_t i = (size_t)blockIdx.x * blockDim.x + threadIdx.x;
    size_t stride = (size_t)gridDim.x * blockDim.x;
    for (; i < n; i += stride) p[i] = 0.f;
}

__global__ __launch_bounds__(256) void hist_kernel(const int* __restrict__ eidx,
                                                   int* __restrict__ cnt) {
    int e = blockIdx.x * 256 + threadIdx.x;
    if (e < N_EDGES) atomicAdd(&cnt[eidx[N_EDGES + e]], 1);
}

__global__ __launch_bounds__(1024) void scan_kernel(const int* __restrict__ cnt,
                                                    int* __restrict__ offs,
                                                    int* __restrict__ fill) {
    __shared__ int s_part[1024];
    const int t = threadIdx.x;
    const int CH = (N_NODES + 1023) / 1024;   // 49
    int i0 = t * CH, i1 = min(i0 + CH, N_NODES);
    int s = 0;
    for (int i = i0; i < i1; ++i) s += cnt[i];
    s_part[t] = s;
    __syncthreads();
    if (t == 0) {
        int run = 0;
        for (int i = 0; i < 1024; ++i) { int v = s_part[i]; s_part[i] = run; run += v; }
    }
    __syncthreads();
    int run = s_part[t];
    for (int i = i0; i < i1; ++i) { offs[i] = run; fill[i] = run; run += cnt[i]; }
}

__global__ __launch_bounds__(256) void scatter_ids_kernel(const int* __restrict__ eidx,
                                                          int* __restrict__ fill,
                                                          int* __restrict__ sorted_eid) {
    int e = blockIdx.x * 256 + threadIdx.x;
    if (e < N_EDGES) {
        int p = atomicAdd(&fill[eidx[N_EDGES + e]], 1);
        sorted_eid[p] = e;
    }
}

// transpose + bf16-convert the MLP weights: w1t[c][k], w2t[c][k]
__global__ __launch_bounds__(256) void prep_w_kernel(const float* __restrict__ w_fc1,
                                                     const float* __restrict__ w_fc2,
                                                     unsigned short* __restrict__ w1t,
                                                     unsigned short* __restrict__ w2t) {
    int i = blockIdx.x * 256 + threadIdx.x;
    if (i < 64 * 64)  { int c = i >> 6, k = i & 63; w1t[i] = f2bf(w_fc1[k * FC_H + c]); }
    if (i < 192 * 64) { int c = i >> 6, k = i & 63; w2t[i] = f2bf(w_fc2[k * W_NUMEL + c]); }
}

// ---------------- fused edge kernel: MFMA MLP + TP features + segmented scatter ----------------

__global__ __launch_bounds__(256) void edge_kernel(
    const float* __restrict__ x,          // N x 160
    const float* __restrict__ es,         // E x 64
    const float* __restrict__ sh,         // E x 4
    const int*   __restrict__ eidx,       // 2 x E
    const int*   __restrict__ sorted_eid, // E
    const unsigned short* __restrict__ w1t,  // 64 x 64  (bf16, [c][k])
    const unsigned short* __restrict__ w2t,  // 192 x 64 (bf16, [c][k])
    float* __restrict__ accg)             // N x 384
{
    __shared__ unsigned short s_h[TILE][FC_H];     // 8KB  (h, bf16)
    __shared__ unsigned short s_w[TILE][W_NUMEL];  // 24KB (weight, bf16)
    __shared__ __align__(16) float s_x[TILE][D_IN];// 40KB
    __shared__ float s_sh[TILE][4];
    __shared__ int   s_eid[TILE], s_src[TILE], s_dst[TILE], s_flush[TILE];

    const int t = threadIdx.x;
    const int tile0 = blockIdx.x * TILE;

    if (t < TILE) {
        int eid = sorted_eid[tile0 + t];
        s_eid[t] = eid;
        s_src[t] = eidx[eid];
        s_dst[t] = eidx[N_EDGES + eid];
    }
    __syncthreads();
    if (t < TILE) s_flush[t] = (t == TILE - 1) || (s_dst[t] != s_dst[t + 1]);
    // stage sh (64 x 4)
    { int e = t >> 2, c4 = t & 3; s_sh[e][c4] = sh[(size_t)s_eid[e] * 4 + c4]; }
    // stage x rows as float4 (64 x 40 float4)
    for (int i = t; i < TILE * 40; i += 256) {
        int e = i / 40, q = i - e * 40;
        ((float4*)s_x[e])[q] = ((const float4*)(x + (size_t)s_src[e] * D_IN))[q];
    }

    // phase-C per-thread feature mapping (hoisted)
    const int f0 = t;
    const int f1 = (t < 128) ? 256 + t : -1;
    int wi0, xi0, si0, mode0; float sc0;
    {
        int f = f0;
        if (f < 64)       { mode0 = 0; wi0 = f;        xi0 = f;          si0 = 0;              sc0 = 1.f; }
        else if (f < 96)  { int uu = f - 64; mode0 = 1; wi0 = 160 + uu; xi0 = 64 + 3 * uu; si0 = 0; sc0 = INV_SQRT3; }
        else if (f < 288) { int kk = f - 96; int uu = kk / 3; mode0 = 0; wi0 = 64 + uu; xi0 = uu; si0 = 1 + (kk - 3 * uu); sc0 = 1.f; }
        else              { int kk = f - 288; mode0 = 0; wi0 = 128 + kk / 3; xi0 = 64 + kk; si0 = 0; sc0 = 1.f; }
    }
    int wi1 = 0, xi1 = 0, si1 = 0;
    if (f1 >= 0) {
        if (f1 < 288) { int kk = f1 - 96; int uu = kk / 3; wi1 = 64 + uu; xi1 = uu; si1 = 1 + (kk - 3 * uu); }
        else          { int kk = f1 - 288; wi1 = 128 + kk / 3; xi1 = 64 + kk; si1 = 0; }
    }

    const int wv = t >> 6;   // wave id: owns edge rows [wv*16, wv*16+16)
    const int l  = t & 63;
    const int lr = l & 15;   // row (A/M) or col (B/N) within 16-tile
    const int lk = l >> 4;   // k-group: elements k = lk*8..lk*8+8 within K=32 step

    // ---- layer 1: h = silu(es @ w_fc1 / 8) * ACT_C  (MFMA) ----
    s16x8 afrag[2];
    {
        const float* rowp = es + (size_t)s_eid[wv * 16 + lr] * FC_H;
#pragma unroll
        for (int kk = 0; kk < 2; ++kk) {
            float4 u = *(const float4*)(rowp + kk * 32 + lk * 8);
            float4 v = *(const float4*)(rowp + kk * 32 + lk * 8 + 4);
            s16x8 a;
            a[0] = f2bf(u.x); a[1] = f2bf(u.y); a[2] = f2bf(u.z); a[3] = f2bf(u.w);
            a[4] = f2bf(v.x); a[5] = f2bf(v.y); a[6] = f2bf(v.z); a[7] = f2bf(v.w);
            afrag[kk] = a;
        }
    }
#pragma unroll
    for (int nt = 0; nt < 4; ++nt) {
        f32x4 hacc = {0.f, 0.f, 0.f, 0.f};
#pragma unroll
        for (int kk = 0; kk < 2; ++kk) {
            s16x8 b = *(const s16x8*)(w1t + (nt * 16 + lr) * 64 + kk * 32 + lk * 8);
            hacc = __builtin_amdgcn_mfma_f32_16x16x32_bf16(afrag[kk], b, hacc, 0, 0, 0);
        }
        // D: col = lr' = l&15 (wait: col = lane&15), row = (l>>4)*4+q
#pragma unroll
        for (int q = 0; q < 4; ++q) {
            float aa = hacc[q] * 0.125f;
            float hv = aa * (1.f / (1.f + __expf(-aa))) * ACT_C;
            s_h[wv * 16 + lk * 4 + q][nt * 16 + lr] = f2bf(hv);
        }
    }

    // ---- layer 2: weight = h @ w_fc2 / 8  (MFMA; h via LDS transpose, intra-wave) ----
    s16x8 hfrag[2];
#pragma unroll
    for (int kk = 0; kk < 2; ++kk)
        hfrag[kk] = *(const s16x8*)(&s_h[wv * 16 + lr][kk * 32 + lk * 8]);
#pragma unroll
    for (int nt = 0; nt < 12; ++nt) {
        f32x4 acc = {0.f, 0.f, 0.f, 0.f};
#pragma unroll
        for (int kk = 0; kk < 2; ++kk) {
            s16x8 b = *(const s16x8*)(w2t + (nt * 16 + lr) * 64 + kk * 32 + lk * 8);
            acc = __builtin_amdgcn_mfma_f32_16x16x32_bf16(hfrag[kk], b, acc, 0, 0, 0);
        }
#pragma unroll
        for (int q = 0; q < 4; ++q)
            s_w[wv * 16 + lk * 4 + q][nt * 16 + lr] = f2bf(acc[q] * 0.125f);
    }
    __syncthreads();   // s_w, s_x, s_sh, s_flush all ready

    // ---- phase C: segmented register accumulation + one atomic per segment ----
    float a0 = 0.f, a1 = 0.f;
#pragma unroll 2
    for (int e = 0; e < TILE; ++e) {
        {
            float W = bf2f(s_w[e][wi0]);
            float v;
            if (mode0) {
                v = W * (s_x[e][xi0]     * s_sh[e][1] +
                         s_x[e][xi0 + 1] * s_sh[e][2] +
                         s_x[e][xi0 + 2] * s_sh[e][3]);
            } else {
                v = W * s_x[e][xi0] * s_sh[e][si0];
            }
            a0 += v;
        }
        if (t < 128) {
            float W = bf2f(s_w[e][wi1]);
            a1 += W * s_x[e][xi1] * s_sh[e][si1];
        }
        if (s_flush[e]) {
            float* dstp = accg + (size_t)s_dst[e] * FEAT;
            atomicAdd(dstp + f0, a0 * sc0);
            a0 = 0.f;
            if (t < 128) { atomicAdd(dstp + f1, a1); a1 = 0.f; }
        }
    }
}

// ---------------- node epilogue ----------------

__global__ __launch_bounds__(256) void node_kernel(
    const float* __restrict__ x,
    const float* __restrict__ accg,
    const int*   __restrict__ cnt,
    const float* __restrict__ w_sc_s,   // 64 x 64
    const float* __restrict__ w_sc_v,   // 32 x 32
    const float* __restrict__ w_lin_s,  // 96 x 64
    const float* __restrict__ w_lin_v,  // 96 x 32
    const float* __restrict__ w_alpha,  // 96
    float* __restrict__ out)            // N x 160
{
    __shared__ float s_m[16][FEAT];
    __shared__ float s_x[16][D_IN];
    __shared__ float s_alpha[16];

    const int t = threadIdx.x;
    const int n0 = blockIdx.x * 16;

    for (int i = t; i < 16 * FEAT; i += 256) {
        int r = i / FEAT, f = i - r * FEAT;
        int n = n0 + r;
        float v = 0.f;
        if (n < N_NODES) {
            float cdiv = 1.f / (float)max(cnt[n], 1);
            v = accg[(size_t)n * FEAT + f] * cdiv;
        }
        s_m[r][f] = v;
    }
    for (int i = t; i < 16 * D_IN; i += 256) {
        int r = i / D_IN, f = i - r * D_IN;
        int n = n0 + r;
        s_x[r][f] = (n < N_NODES) ? x[(size_t)n * D_IN + f] : 0.f;
    }
    __syncthreads();

    if (t < 16) {
        float a = 0.f;
        for (int uu = 0; uu < 96; ++uu) a += s_m[t][uu] * w_alpha[uu];
        s_alpha[t] = a * RSQRT96;
    }
    __syncthreads();

    if (t < 160) {
        const int c = t;
        float scv[16], lin[16];
#pragma unroll
        for (int r = 0; r < 16; ++r) { scv[r] = 0.f; lin[r] = 0.f; }
        if (c < 64) {
            for (int uu = 0; uu < 64; ++uu) {
                float w = w_sc_s[uu * 64 + c];
#pragma unroll
                for (int r = 0; r < 16; ++r) scv[r] += s_x[r][uu] * w;
            }
            for (int uu = 0; uu < 96; ++uu) {
                float w = w_lin_s[uu * 64 + c];
#pragma unroll
                for (int r = 0; r < 16; ++r) lin[r] += s_m[r][uu] * w;
            }
#pragma unroll
            for (int r = 0; r < 16; ++r) {
                int n = n0 + r;
                if (n < N_NODES)
                    out[(size_t)n * 160 + c] = scv[r] * 0.125f + s_alpha[r] * lin[r] * RSQRT96;
            }
        } else {
            const int k = c - 64;
            const int wcol = k / 3;
            const int ii = k - wcol * 3;
            for (int uu = 0; uu < 32; ++uu) {
                float w = w_sc_v[uu * 32 + wcol];
#pragma unroll
                for (int r = 0; r < 16; ++r) scv[r] += s_x[r][64 + uu * 3 + ii] * w;
            }
            for (int uu = 0; uu < 96; ++uu) {
                float w = w_lin_v[uu * 32 + wcol];
#pragma unroll
                for (int r = 0; r < 16; ++r) lin[r] += s_m[r][96 + uu * 3 + ii] * w;
            }
#pragma unroll
            for (int r = 0; r < 16; ++r) {
                int n = n0 + r;
                if (n < N_NODES)
                    out[(size_t)n * 160 + c] = scv[r] * RSQRT32 + s_alpha[r] * lin[r] * RSQRT96;
            }
        }
    }
}

// ---------------- launch ----------------

extern "C" void kernel_launch(void* const* d_in, const int* in_sizes, int n_in,
                              void* d_out, int out_size, void* d_ws, size_t ws_size,
                              hipStream_t stream) {
    const float* x        = (const float*)d_in[0];
    const float* es       = (const float*)d_in[1];
    const float* sh       = (const float*)d_in[2];
    const int*   eidx     = (const int*)d_in[3];
    const float* w_fc1    = (const float*)d_in[4];
    const float* w_fc2    = (const float*)d_in[5];
    const float* w_sc_s   = (const float*)d_in[6];
    const float* w_sc_v   = (const float*)d_in[7];
    const float* w_lin_s  = (const float*)d_in[8];
    const float* w_lin_v  = (const float*)d_in[9];
    const float* w_alpha  = (const float*)d_in[10];
    float* out = (float*)d_out;

    // workspace layout (4-byte words; w1t offset is 16B-aligned)
    float* accg       = (float*)d_ws;                                  // N*384
    int*   cnt        = (int*)(accg + (size_t)N_NODES * FEAT);         // N
    int*   offs       = cnt + N_NODES;                                 // N
    int*   fill       = offs + N_NODES;                                // N
    int*   sorted_eid = fill + N_NODES;                                // E
    unsigned short* w1t = (unsigned short*)(sorted_eid + N_EDGES);     // 64*64 bf16
    unsigned short* w2t = w1t + 64 * 64;                               // 192*64 bf16

    hipLaunchKernelGGL(zero_kernel, dim3(2048), dim3(256), 0, stream,
                       accg, (size_t)N_NODES * (FEAT + 1));
    hipLaunchKernelGGL(hist_kernel, dim3((N_EDGES + 255) / 256), dim3(256), 0, stream,
                       eidx, cnt);
    hipLaunchKernelGGL(scan_kernel, dim3(1), dim3(1024), 0, stream, cnt, offs, fill);
    hipLaunchKernelGGL(scatter_ids_kernel, dim3((N_EDGES + 255) / 256), dim3(256), 0, stream,
                       eidx, fill, sorted_eid);
    hipLaunchKernelGGL(prep_w_kernel, dim3(48), dim3(256), 0, stream,
                       w_fc1, w_fc2, w1t, w2t);
    hipLaunchKernelGGL(edge_kernel, dim3(N_EDGES / TILE), dim3(256), 0, stream,
                       x, es, sh, eidx, sorted_eid, w1t, w2t, accg);
    hipLaunchKernelGGL(node_kernel, dim3((N_NODES + 15) / 16), dim3(256), 0, stream,
                       x, accg, cnt, w_sc_s, w_sc_v, w_lin_s, w_lin_v, w_alpha, out);
}

// Round 4
// 622.640 us; speedup vs baseline: 3.1263x; 1.6709x over previous
//
#include <hip/hip_runtime.h>

#define N_NODES 50000
#define N_EDGES 800000
#define MUL0 64
#define MUL1 32
#define D_IN 160      // 64 + 3*32
#define FC_H 64
#define W_NUMEL 192   // 64+64+32+32
#define FEAT 384      // 64 + 32 + 192 + 96
#define ACT_C 1.6791f
#define INV_SQRT3 0.57735026918962576f
#define RSQRT32 0.17677669529663687f
#define RSQRT96 0.10206207261596575f

#define TILE 64       // edges per block (sorted by dst)

typedef __attribute__((ext_vector_type(8))) short s16x8;
typedef __attribute__((ext_vector_type(4))) float f32x4;

static __device__ __forceinline__ unsigned short f2bf(float f) {
    unsigned u = __builtin_bit_cast(unsigned, f);
    unsigned r = (u + 0x7fffu + ((u >> 16) & 1u)) >> 16;   // RNE
    return (unsigned short)r;
}
static __device__ __forceinline__ float bf2f(unsigned short b) {
    return __builtin_bit_cast(float, (unsigned)b << 16);
}

// ---------------- utility kernels ----------------

__global__ __launch_bounds__(256) void hist_kernel(const int* __restrict__ eidx,
                                                   int* __restrict__ cnt) {
    int e = blockIdx.x * 256 + threadIdx.x;
    if (e < N_EDGES) atomicAdd(&cnt[eidx[N_EDGES + e]], 1);
}

__global__ __launch_bounds__(1024) void scan_kernel(const int* __restrict__ cnt,
                                                    int* __restrict__ fill) {
    __shared__ int s_wsum[16];
    const int t = threadIdx.x;
    const int CH = (N_NODES + 1023) / 1024;   // 49
    int i0 = t * CH, i1 = min(i0 + CH, N_NODES);
    int s = 0;
    for (int i = i0; i < i1; ++i) s += cnt[i];
    int v = s;
    for (int d = 1; d < 64; d <<= 1) {
        int u = __shfl_up(v, d);
        if ((t & 63) >= d) v += u;
    }
    if ((t & 63) == 63) s_wsum[t >> 6] = v;
    __syncthreads();
    if (t == 0) {
        int run = 0;
        for (int w = 0; w < 16; ++w) { int tv = s_wsum[w]; s_wsum[w] = run; run += tv; }
    }
    __syncthreads();
    int run = s_wsum[t >> 6] + (v - s);   // exclusive prefix for this thread
    for (int i = i0; i < i1; ++i) { fill[i] = run; run += cnt[i]; }
}

__global__ __launch_bounds__(256) void scatter_ids_kernel(const int* __restrict__ eidx,
                                                          int* __restrict__ fill,
                                                          int* __restrict__ sorted_eid) {
    int e = blockIdx.x * 256 + threadIdx.x;
    if (e < N_EDGES) {
        int p = atomicAdd(&fill[eidx[N_EDGES + e]], 1);
        sorted_eid[p] = e;
    }
}

// transpose + bf16-convert all GEMM weights
__global__ __launch_bounds__(256) void prep_w_kernel(
    const float* __restrict__ w_fc1,   // 64 x 64
    const float* __restrict__ w_fc2,   // 64 x 192
    const float* __restrict__ w_sc_s,  // 64 x 64
    const float* __restrict__ w_sc_v,  // 32 x 32
    const float* __restrict__ w_lin_s, // 96 x 64
    const float* __restrict__ w_lin_v, // 96 x 32
    unsigned short* __restrict__ w1t,    // [64][64]
    unsigned short* __restrict__ w2t,    // [192][64]
    unsigned short* __restrict__ wscs_t, // [64][64]
    unsigned short* __restrict__ wscv_t, // [32][32]
    unsigned short* __restrict__ wlins_t,// [64][96]
    unsigned short* __restrict__ wlinv_t)// [32][96]
{
    int i = blockIdx.x * 256 + threadIdx.x;
    if (i < 64 * 64)  w1t[i]    = f2bf(w_fc1[(i & 63) * FC_H + (i >> 6)]);
    if (i < 192 * 64) w2t[i]    = f2bf(w_fc2[(i & 63) * W_NUMEL + (i >> 6)]);
    if (i < 64 * 64)  wscs_t[i] = f2bf(w_sc_s[(i & 63) * 64 + (i >> 6)]);
    if (i < 32 * 32)  wscv_t[i] = f2bf(w_sc_v[(i & 31) * 32 + (i >> 5)]);
    if (i < 64 * 96)  wlins_t[i] = f2bf(w_lin_s[(i % 96) * 64 + (i / 96)]);
    if (i < 32 * 96)  wlinv_t[i] = f2bf(w_lin_v[(i % 96) * 32 + (i / 96)]);
}

// ---------------- fused edge kernel ----------------

__global__ __launch_bounds__(256) void edge_kernel(
    const float* __restrict__ x,          // N x 160
    const float* __restrict__ es,         // E x 64
    const float* __restrict__ sh,         // E x 4
    const int*   __restrict__ eidx,       // 2 x E
    const int*   __restrict__ sorted_eid, // E
    const unsigned short* __restrict__ w1t,  // [64][64]  bf16
    const unsigned short* __restrict__ w2t,  // [192][64] bf16
    float* __restrict__ accg)             // N x 384
{
    __shared__ unsigned short s_w[TILE][W_NUMEL];  // 24KB; cols 0..63 double as h
    __shared__ unsigned short s_x[TILE][D_IN];     // 20KB (bf16)
    __shared__ float s_sh[TILE][4];
    __shared__ int   s_eid[TILE], s_src[TILE], s_dst[TILE], s_flush[TILE];

    const int t = threadIdx.x;
    const int tile0 = blockIdx.x * TILE;

    if (t < TILE) {
        int eid = sorted_eid[tile0 + t];
        s_eid[t] = eid;
        s_src[t] = eidx[eid];
        s_dst[t] = eidx[N_EDGES + eid];
    }
    __syncthreads();
    if (t < TILE) s_flush[t] = (t == TILE - 1) || (s_dst[t] != s_dst[t + 1]);

    // ---- issue gather loads into REGISTERS (T14: write LDS after MLP) ----
    float shval = sh[(size_t)s_eid[t >> 2] * 4 + (t & 3)];
    float4 xg[10];
#pragma unroll
    for (int q = 0; q < 10; ++q) {
        int i = q * 256 + t;
        int e = i / 40, c4 = i - e * 40;
        xg[q] = ((const float4*)(x + (size_t)s_src[e] * D_IN))[c4];
    }

    // phase-C per-thread feature mapping
    const int f0 = t;
    const int f1 = (t < 128) ? 256 + t : -1;
    int wi0, xi0, si0, mode0; float sc0;
    {
        int f = f0;
        if (f < 64)       { mode0 = 0; wi0 = f;        xi0 = f;          si0 = 0;              sc0 = 1.f; }
        else if (f < 96)  { int uu = f - 64; mode0 = 1; wi0 = 160 + uu; xi0 = 64 + 3 * uu; si0 = 0; sc0 = INV_SQRT3; }
        else if (f < 288) { int kk = f - 96; int uu = kk / 3; mode0 = 0; wi0 = 64 + uu; xi0 = uu; si0 = 1 + (kk - 3 * uu); sc0 = 1.f; }
        else              { int kk = f - 288; mode0 = 0; wi0 = 128 + kk / 3; xi0 = 64 + kk; si0 = 0; sc0 = 1.f; }
    }
    int wi1 = 0, xi1 = 0, si1 = 0;
    if (f1 >= 0) {
        if (f1 < 288) { int kk = f1 - 96; int uu = kk / 3; wi1 = 64 + uu; xi1 = uu; si1 = 1 + (kk - 3 * uu); }
        else          { int kk = f1 - 288; wi1 = 128 + kk / 3; xi1 = 64 + kk; si1 = 0; }
    }

    const int wv = t >> 6;   // wave owns edge rows [wv*16, wv*16+16)
    const int l  = t & 63;
    const int lr = l & 15;
    const int lk = l >> 4;

    // ---- layer 1: h = silu(es @ w_fc1 / 8) * ACT_C ----
    s16x8 afrag[2];
    {
        const float* rowp = es + (size_t)s_eid[wv * 16 + lr] * FC_H;
#pragma unroll
        for (int kk = 0; kk < 2; ++kk) {
            float4 u = *(const float4*)(rowp + kk * 32 + lk * 8);
            float4 v = *(const float4*)(rowp + kk * 32 + lk * 8 + 4);
            s16x8 a;
            a[0] = f2bf(u.x); a[1] = f2bf(u.y); a[2] = f2bf(u.z); a[3] = f2bf(u.w);
            a[4] = f2bf(v.x); a[5] = f2bf(v.y); a[6] = f2bf(v.z); a[7] = f2bf(v.w);
            afrag[kk] = a;
        }
    }
#pragma unroll
    for (int nt = 0; nt < 4; ++nt) {
        f32x4 hacc = {0.f, 0.f, 0.f, 0.f};
#pragma unroll
        for (int kk = 0; kk < 2; ++kk) {
            s16x8 b = *(const s16x8*)(w1t + (nt * 16 + lr) * 64 + kk * 32 + lk * 8);
            hacc = __builtin_amdgcn_mfma_f32_16x16x32_bf16(afrag[kk], b, hacc, 0, 0, 0);
        }
#pragma unroll
        for (int q = 0; q < 4; ++q) {
            float aa = hacc[q] * 0.125f;
            float hv = aa * (1.f / (1.f + __expf(-aa))) * ACT_C;
            s_w[wv * 16 + lk * 4 + q][nt * 16 + lr] = f2bf(hv);   // h lives in cols 0..63
        }
    }

    // ---- layer 2: weight = h @ w_fc2 / 8 (h read before cols 0..63 overwritten; intra-wave) ----
    s16x8 hfrag[2];
#pragma unroll
    for (int kk = 0; kk < 2; ++kk)
        hfrag[kk] = *(const s16x8*)(&s_w[wv * 16 + lr][kk * 32 + lk * 8]);
#pragma unroll
    for (int nt = 0; nt < 12; ++nt) {
        f32x4 acc = {0.f, 0.f, 0.f, 0.f};
#pragma unroll
        for (int kk = 0; kk < 2; ++kk) {
            s16x8 b = *(const s16x8*)(w2t + (nt * 16 + lr) * 64 + kk * 32 + lk * 8);
            acc = __builtin_amdgcn_mfma_f32_16x16x32_bf16(hfrag[kk], b, acc, 0, 0, 0);
        }
#pragma unroll
        for (int q = 0; q < 4; ++q)
            s_w[wv * 16 + lk * 4 + q][nt * 16 + lr] = f2bf(acc[q] * 0.125f);
    }

    // ---- write staged gather to LDS (loads have had the MLP to complete under) ----
    s_sh[t >> 2][t & 3] = shval;
#pragma unroll
    for (int q = 0; q < 10; ++q) {
        int i = q * 256 + t;
        int e = i / 40, c4 = i - e * 40;
        unsigned short b4[4] = { f2bf(xg[q].x), f2bf(xg[q].y), f2bf(xg[q].z), f2bf(xg[q].w) };
        *(uint2*)&s_x[e][c4 * 4] = *(uint2*)b4;
    }
    __syncthreads();

    // ---- phase C: segmented register accumulation + one atomic per segment ----
    float a0 = 0.f, a1 = 0.f;
#pragma unroll 2
    for (int e = 0; e < TILE; ++e) {
        {
            float W = bf2f(s_w[e][wi0]);
            float v;
            if (mode0) {
                v = W * (bf2f(s_x[e][xi0])     * s_sh[e][1] +
                         bf2f(s_x[e][xi0 + 1]) * s_sh[e][2] +
                         bf2f(s_x[e][xi0 + 2]) * s_sh[e][3]);
            } else {
                v = W * bf2f(s_x[e][xi0]) * s_sh[e][si0];
            }
            a0 += v;
        }
        if (t < 128) {
            float W = bf2f(s_w[e][wi1]);
            a1 += W * bf2f(s_x[e][xi1]) * s_sh[e][si1];
        }
        if (s_flush[e]) {
            float* dstp = accg + (size_t)s_dst[e] * FEAT;
            atomicAdd(dstp + f0, a0 * sc0);
            a0 = 0.f;
            if (t < 128) { atomicAdd(dstp + f1, a1); a1 = 0.f; }
        }
    }
}

// ---------------- node epilogue (MFMA) ----------------

static __device__ __forceinline__ s16x8 frag_c8(const float* p, float s) {
    float4 u = *(const float4*)p, v = *(const float4*)(p + 4);
    s16x8 a;
    a[0] = f2bf(u.x * s); a[1] = f2bf(u.y * s); a[2] = f2bf(u.z * s); a[3] = f2bf(u.w * s);
    a[4] = f2bf(v.x * s); a[5] = f2bf(v.y * s); a[6] = f2bf(v.z * s); a[7] = f2bf(v.w * s);
    return a;
}
static __device__ __forceinline__ s16x8 frag_s3(const float* p, float s) {
    s16x8 a;
#pragma unroll
    for (int j = 0; j < 8; ++j) a[j] = f2bf(p[j * 3] * s);
    return a;
}

__global__ __launch_bounds__(256) void node_kernel(
    const float* __restrict__ x,
    const float* __restrict__ accg,
    const int*   __restrict__ cnt,
    const unsigned short* __restrict__ wscs_t,  // [64][64]
    const unsigned short* __restrict__ wscv_t,  // [32][32]
    const unsigned short* __restrict__ wlins_t, // [64][96]
    const unsigned short* __restrict__ wlinv_t, // [32][96]
    const float* __restrict__ w_alpha,          // 96
    float* __restrict__ out)                    // N x 160
{
    const int t = threadIdx.x;
    const int wv = t >> 6, l = t & 63;
    const int lr = l & 15, lk = l >> 4;
    const int n_base = blockIdx.x * 64 + wv * 16;
    const int nrow = n_base + lr;
    const int nclamp = min(nrow, N_NODES - 1);

    const float* mrow = accg + (size_t)nclamp * FEAT;
    const float* xrow = x + (size_t)nclamp * D_IN;
    const float rinv = 1.f / (float)max(cnt[nclamp], 1);

    // A fragments
    s16x8 ax[2], ams[3], axv[3], amv[3][3];
#pragma unroll
    for (int kk = 0; kk < 2; ++kk) ax[kk] = frag_c8(xrow + kk * 32 + lk * 8, 1.f);
#pragma unroll
    for (int kk = 0; kk < 3; ++kk) ams[kk] = frag_c8(mrow + kk * 32 + lk * 8, rinv);
#pragma unroll
    for (int i = 0; i < 3; ++i) axv[i] = frag_s3(xrow + 64 + 3 * (lk * 8) + i, 1.f);
#pragma unroll
    for (int i = 0; i < 3; ++i)
#pragma unroll
        for (int kk = 0; kk < 3; ++kk)
            amv[i][kk] = frag_s3(mrow + 96 + 3 * (kk * 32 + lk * 8) + i, rinv);

    // alpha[n] = (m_s . w_alpha) * RSQRT96
    float ap = 0.f;
#pragma unroll
    for (int j = 0; j < 24; ++j) ap += mrow[lk * 24 + j] * rinv * w_alpha[lk * 24 + j];
    ap += __shfl_xor(ap, 16);
    ap += __shfl_xor(ap, 32);
    const float alphav = ap * RSQRT96;

    // s-cols: sc_s (K=64) and lin_s (K=96), N=64
    f32x4 accA[4], accL[4];
#pragma unroll
    for (int nt = 0; nt < 4; ++nt) { accA[nt] = (f32x4){0,0,0,0}; accL[nt] = (f32x4){0,0,0,0}; }
#pragma unroll
    for (int nt = 0; nt < 4; ++nt) {
#pragma unroll
        for (int kk = 0; kk < 2; ++kk) {
            s16x8 b = *(const s16x8*)(wscs_t + (nt * 16 + lr) * 64 + kk * 32 + lk * 8);
            accA[nt] = __builtin_amdgcn_mfma_f32_16x16x32_bf16(ax[kk], b, accA[nt], 0, 0, 0);
        }
#pragma unroll
        for (int kk = 0; kk < 3; ++kk) {
            s16x8 b = *(const s16x8*)(wlins_t + (nt * 16 + lr) * 96 + kk * 32 + lk * 8);
            accL[nt] = __builtin_amdgcn_mfma_f32_16x16x32_bf16(ams[kk], b, accL[nt], 0, 0, 0);
        }
    }
    // v-cols: sc_v (K=32) and lin_v (K=96), N=32, per i
    f32x4 accVs[3][2], accVl[3][2];
#pragma unroll
    for (int i = 0; i < 3; ++i)
#pragma unroll
        for (int nt = 0; nt < 2; ++nt) { accVs[i][nt] = (f32x4){0,0,0,0}; accVl[i][nt] = (f32x4){0,0,0,0}; }
#pragma unroll
    for (int i = 0; i < 3; ++i) {
#pragma unroll
        for (int nt = 0; nt < 2; ++nt) {
            s16x8 b = *(const s16x8*)(wscv_t + (nt * 16 + lr) * 32 + lk * 8);
            accVs[i][nt] = __builtin_amdgcn_mfma_f32_16x16x32_bf16(axv[i], b, accVs[i][nt], 0, 0, 0);
#pragma unroll
            for (int kk = 0; kk < 3; ++kk) {
                s16x8 b2 = *(const s16x8*)(wlinv_t + (nt * 16 + lr) * 96 + kk * 32 + lk * 8);
                accVl[i][nt] = __builtin_amdgcn_mfma_f32_16x16x32_bf16(amv[i][kk], b2, accVl[i][nt], 0, 0, 0);
            }
        }
    }

    // combine + store. D layout: col = lane&15, row = (lane>>4)*4 + q
#pragma unroll
    for (int q = 0; q < 4; ++q) {
        int row = lk * 4 + q;
        float ar = __shfl(alphav, row);
        int n = n_base + row;
        bool ok = (n < N_NODES);
        float* orow = out + (size_t)n * 160;
#pragma unroll
        for (int nt = 0; nt < 4; ++nt) {
            float vout = accA[nt][q] * 0.125f + ar * accL[nt][q] * RSQRT96;
            if (ok) orow[nt * 16 + lr] = vout;
        }
#pragma unroll
        for (int i = 0; i < 3; ++i)
#pragma unroll
            for (int nt = 0; nt < 2; ++nt) {
                float vout = accVs[i][nt][q] * RSQRT32 + ar * accVl[i][nt][q] * RSQRT96;
                if (ok) orow[64 + 3 * (nt * 16 + lr) + i] = vout;
            }
    }
}

// ---------------- launch ----------------

extern "C" void kernel_launch(void* const* d_in, const int* in_sizes, int n_in,
                              void* d_out, int out_size, void* d_ws, size_t ws_size,
                              hipStream_t stream) {
    const float* x        = (const float*)d_in[0];
    const float* es       = (const float*)d_in[1];
    const float* sh       = (const float*)d_in[2];
    const int*   eidx     = (const int*)d_in[3];
    const float* w_fc1    = (const float*)d_in[4];
    const float* w_fc2    = (const float*)d_in[5];
    const float* w_sc_s   = (const float*)d_in[6];
    const float* w_sc_v   = (const float*)d_in[7];
    const float* w_lin_s  = (const float*)d_in[8];
    const float* w_lin_v  = (const float*)d_in[9];
    const float* w_alpha  = (const float*)d_in[10];
    float* out = (float*)d_out;

    // workspace layout (all 16B-aligned)
    float* accg       = (float*)d_ws;                                  // N*384
    int*   cnt        = (int*)(accg + (size_t)N_NODES * FEAT);         // N
    int*   fill       = cnt + N_NODES;                                 // N
    int*   sorted_eid = fill + N_NODES;                                // E
    unsigned short* w1t     = (unsigned short*)(sorted_eid + N_EDGES); // 64*64
    unsigned short* w2t     = w1t + 64 * 64;                           // 192*64
    unsigned short* wscs_t  = w2t + 192 * 64;                          // 64*64
    unsigned short* wscv_t  = wscs_t + 64 * 64;                        // 32*32
    unsigned short* wlins_t = wscv_t + 32 * 32;                        // 64*96
    unsigned short* wlinv_t = wlins_t + 64 * 96;                       // 32*96

    hipMemsetAsync(d_ws, 0, ((size_t)N_NODES * FEAT + N_NODES) * 4, stream);
    hipLaunchKernelGGL(hist_kernel, dim3((N_EDGES + 255) / 256), dim3(256), 0, stream,
                       eidx, cnt);
    hipLaunchKernelGGL(scan_kernel, dim3(1), dim3(1024), 0, stream, cnt, fill);
    hipLaunchKernelGGL(scatter_ids_kernel, dim3((N_EDGES + 255) / 256), dim3(256), 0, stream,
                       eidx, fill, sorted_eid);
    hipLaunchKernelGGL(prep_w_kernel, dim3(48), dim3(256), 0, stream,
                       w_fc1, w_fc2, w_sc_s, w_sc_v, w_lin_s, w_lin_v,
                       w1t, w2t, wscs_t, wscv_t, wlins_t, wlinv_t);
    hipLaunchKernelGGL(edge_kernel, dim3(N_EDGES / TILE), dim3(256), 0, stream,
                       x, es, sh, eidx, sorted_eid, w1t, w2t, accg);
    hipLaunchKernelGGL(node_kernel, dim3((N_NODES + 63) / 64), dim3(256), 0, stream,
                       x, accg, cnt, wscs_t, wscv_t, wlins_t, wlinv_t, w_alpha, out);
}

// Round 6
// 540.254 us; speedup vs baseline: 3.6030x; 1.1525x over previous
//
#include <hip/hip_runtime.h>

#define N_NODES 50000
#define N_EDGES 800000
#define MUL0 64
#define MUL1 32
#define D_IN 160      // 64 + 3*32
#define FC_H 64
#define W_NUMEL 192   // 64+64+32+32
#define FEAT 384      // 64 + 32 + 192 + 96
#define ACT_C 1.6791f
#define INV_SQRT3 0.57735026918962576f
#define RSQRT32 0.17677669529663687f
#define RSQRT96 0.10206207261596575f

#define TILE 64       // edges per block (sorted by dst)

typedef __attribute__((ext_vector_type(8))) short s16x8;
typedef __attribute__((ext_vector_type(4))) float f32x4;
typedef _Float16 h8 __attribute__((ext_vector_type(8)));
typedef __fp16 fp16x2 __attribute__((ext_vector_type(2)));

static __device__ __forceinline__ unsigned short f2bf(float f) {
    unsigned u = __builtin_bit_cast(unsigned, f);
    unsigned r = (u + 0x7fffu + ((u >> 16) & 1u)) >> 16;   // RNE
    return (unsigned short)r;
}

// transposed f16 LDS tile access: layout [row][64 edges], 128B rows,
// XOR-swizzle in 16B units so column (edge-slice) b128 reads spread banks.
static __device__ __forceinline__ h8 lds_h8(const unsigned char* base, int row, int ebyte) {
    int b = (row * 128 + ebyte) ^ ((row & 7) << 4);
    return *(const h8*)(base + b);
}

// ---------------- utility kernels ----------------

__global__ __launch_bounds__(256) void hist_kernel(const int* __restrict__ eidx,
                                                   int* __restrict__ cnt) {
    int e = blockIdx.x * 256 + threadIdx.x;
    if (e < N_EDGES) atomicAdd(&cnt[eidx[N_EDGES + e]], 1);
}

__global__ __launch_bounds__(1024) void scan_kernel(const int* __restrict__ cnt,
                                                    int* __restrict__ fill) {
    __shared__ int s_wsum[16];
    const int t = threadIdx.x;
    const int CH = (N_NODES + 1023) / 1024;   // 49
    int i0 = t * CH, i1 = min(i0 + CH, N_NODES);
    int s = 0;
    for (int i = i0; i < i1; ++i) s += cnt[i];
    int v = s;
    for (int d = 1; d < 64; d <<= 1) {
        int u = __shfl_up(v, d);
        if ((t & 63) >= d) v += u;
    }
    if ((t & 63) == 63) s_wsum[t >> 6] = v;
    __syncthreads();
    if (t == 0) {
        int run = 0;
        for (int w = 0; w < 16; ++w) { int tv = s_wsum[w]; s_wsum[w] = run; run += tv; }
    }
    __syncthreads();
    int run = s_wsum[t >> 6] + (v - s);
    for (int i = i0; i < i1; ++i) { fill[i] = run; run += cnt[i]; }
}

__global__ __launch_bounds__(256) void scatter_ids_kernel(const int* __restrict__ eidx,
                                                          int* __restrict__ fill,
                                                          int* __restrict__ sorted_eid) {
    int e = blockIdx.x * 256 + threadIdx.x;
    if (e < N_EDGES) {
        int p = atomicAdd(&fill[eidx[N_EDGES + e]], 1);
        sorted_eid[p] = e;
    }
}

__global__ __launch_bounds__(256) void prep_w_kernel(
    const float* __restrict__ w_fc1,
    const float* __restrict__ w_fc2,
    const float* __restrict__ w_sc_s,
    const float* __restrict__ w_sc_v,
    const float* __restrict__ w_lin_s,
    const float* __restrict__ w_lin_v,
    unsigned short* __restrict__ w1t,    // [64][64]
    unsigned short* __restrict__ w2t,    // [192][64]
    unsigned short* __restrict__ wscs_t, // [64][64]
    unsigned short* __restrict__ wscv_t, // [32][32]
    unsigned short* __restrict__ wlins_t,// [64][96]
    unsigned short* __restrict__ wlinv_t)// [32][96]
{
    int i = blockIdx.x * 256 + threadIdx.x;
    if (i < 64 * 64)  w1t[i]    = f2bf(w_fc1[(i & 63) * FC_H + (i >> 6)]);
    if (i < 192 * 64) w2t[i]    = f2bf(w_fc2[(i & 63) * W_NUMEL + (i >> 6)]);
    if (i < 64 * 64)  wscs_t[i] = f2bf(w_sc_s[(i & 63) * 64 + (i >> 6)]);
    if (i < 32 * 32)  wscv_t[i] = f2bf(w_sc_v[(i & 31) * 32 + (i >> 5)]);
    if (i < 64 * 96)  wlins_t[i] = f2bf(w_lin_s[(i % 96) * 64 + (i / 96)]);
    if (i < 32 * 96)  wlinv_t[i] = f2bf(w_lin_v[(i % 96) * 32 + (i / 96)]);
}

// ---------------- fused edge kernel ----------------
// LDS regions (bytes):
#define X_OFF    0        // xT f16 [160][64] = 20480 ; first 8KB aliased as h bf16[64][64]
#define W_OFF    20480    // wT f16 [192][64] = 24576
#define SH_OFF   45056    // shT f16 [4][64] = 512
#define SID_OFF  45568    // u16 [64]
#define SEGN_OFF 45696    // int [64]
#define SRC_OFF  45952    // int [64]
#define DST_OFF  46208    // int [64]
#define EID_OFF  46464    // int [64]
#define NSEG_OFF 46720
#define SMEM_SZ  46848

__global__ __launch_bounds__(256) void edge_kernel(
    const float* __restrict__ x,
    const float* __restrict__ es,
    const float* __restrict__ sh,
    const int*   __restrict__ eidx,
    const int*   __restrict__ sorted_eid,
    const unsigned short* __restrict__ w1t,  // [64][64]  bf16
    const unsigned short* __restrict__ w2t,  // [192][64] bf16
    float* __restrict__ accg)
{
    __shared__ __align__(16) unsigned char smem[SMEM_SZ];
    int* s_src = (int*)(smem + SRC_OFF);
    int* s_dst = (int*)(smem + DST_OFF);
    int* s_eid = (int*)(smem + EID_OFF);
    int* s_segnode = (int*)(smem + SEGN_OFF);
    unsigned short* s_sid = (unsigned short*)(smem + SID_OFF);

    const int t = threadIdx.x;
    const int l = t & 63;
    const int wv = t >> 6;
    const int lr = l & 15;
    const int lk = l >> 4;
    const int tile0 = blockIdx.x * TILE;

    if (t < TILE) {
        int eid = sorted_eid[tile0 + t];
        s_eid[t] = eid;
        s_src[t] = eidx[eid];
        s_dst[t] = eidx[N_EDGES + eid];
    }
    __syncthreads();

    // segment ids via ballot prefix (wave 0)
    if (t < TILE) {
        bool flag = (t == TILE - 1) || (s_dst[t] != s_dst[t + 1]);
        unsigned long long mask = __ballot(flag);
        int sid = __popcll(mask & ((1ull << t) - 1ull));
        s_sid[t] = (unsigned short)sid;
        if (flag) s_segnode[sid] = s_dst[t];
        if (t == TILE - 1) *(int*)(smem + NSEG_OFF) = sid + 1;
    }

    // T14 gather: wave wv loads float4-chunks [wv*10, wv*10+10) of all 64 edge rows
    const float* xrow = x + (size_t)s_src[l] * D_IN;
    float4 xg[10];
#pragma unroll
    for (int k = 0; k < 10; ++k) xg[k] = ((const float4*)xrow)[wv * 10 + k];
    float shv = sh[(size_t)s_eid[t >> 2] * 4 + (t & 3)];

    // ---- layer 1: h = silu(es @ w_fc1 / 8) * ACT_C  (bf16 MFMA) ----
    unsigned short* s_h = (unsigned short*)(smem + X_OFF);   // bf16 [64][64], aliased
    s16x8 afrag[2];
    {
        const float* esp = es + (size_t)s_eid[wv * 16 + lr] * FC_H;
#pragma unroll
        for (int kk = 0; kk < 2; ++kk) {
            float4 u = *(const float4*)(esp + kk * 32 + lk * 8);
            float4 v = *(const float4*)(esp + kk * 32 + lk * 8 + 4);
            s16x8 a;
            a[0] = f2bf(u.x); a[1] = f2bf(u.y); a[2] = f2bf(u.z); a[3] = f2bf(u.w);
            a[4] = f2bf(v.x); a[5] = f2bf(v.y); a[6] = f2bf(v.z); a[7] = f2bf(v.w);
            afrag[kk] = a;
        }
    }
#pragma unroll
    for (int nt = 0; nt < 4; ++nt) {
        f32x4 hacc = {0.f, 0.f, 0.f, 0.f};
#pragma unroll
        for (int kk = 0; kk < 2; ++kk) {
            s16x8 b = *(const s16x8*)(w1t + (nt * 16 + lr) * 64 + kk * 32 + lk * 8);
            hacc = __builtin_amdgcn_mfma_f32_16x16x32_bf16(afrag[kk], b, hacc, 0, 0, 0);
        }
#pragma unroll
        for (int q = 0; q < 4; ++q) {
            float aa = hacc[q] * 0.125f;
            float hv = aa * (1.f / (1.f + __expf(-aa))) * ACT_C;
            s_h[(wv * 16 + lk * 4 + q) * 64 + nt * 16 + lr] = f2bf(hv);
        }
    }
    // own-row h fragments (intra-wave dependency only)
    s16x8 hfrag[2];
#pragma unroll
    for (int kk = 0; kk < 2; ++kk)
        hfrag[kk] = *(const s16x8*)(s_h + (wv * 16 + lr) * 64 + kk * 32 + lk * 8);
    __syncthreads();   // all h reads done; X region may now be overwritten

    // ---- layer 2: weight = h @ w_fc2 / 8 -> transposed f16 wT ----
#pragma unroll
    for (int nt = 0; nt < 12; ++nt) {
        f32x4 acc = {0.f, 0.f, 0.f, 0.f};
#pragma unroll
        for (int kk = 0; kk < 2; ++kk) {
            s16x8 b = *(const s16x8*)(w2t + (nt * 16 + lr) * 64 + kk * 32 + lk * 8);
            acc = __builtin_amdgcn_mfma_f32_16x16x32_bf16(hfrag[kk], b, acc, 0, 0, 0);
        }
        int f = nt * 16 + lr;
        fp16x2 p0 = __builtin_amdgcn_cvt_pkrtz(acc[0] * 0.125f, acc[1] * 0.125f);
        fp16x2 p1 = __builtin_amdgcn_cvt_pkrtz(acc[2] * 0.125f, acc[3] * 0.125f);
        uint2 wval = { __builtin_bit_cast(unsigned, p0), __builtin_bit_cast(unsigned, p1) };
        int b = (f * 128 + (wv * 16 + lk * 4) * 2) ^ ((f & 7) << 4);
        *(uint2*)(smem + W_OFF + b) = wval;   // 4 consecutive edges of col f
    }

    // ---- write gathered x (f16, transposed) + sh ----
#pragma unroll
    for (int k = 0; k < 10; ++k) {
        float4 v = xg[k];
#pragma unroll
        for (int jj = 0; jj < 4; ++jj) {
            int r = (wv * 10 + k) * 4 + jj;
            float fv = (jj == 0) ? v.x : (jj == 1) ? v.y : (jj == 2) ? v.z : v.w;
            int b = (r * 128 + l * 2) ^ ((r & 7) << 4);
            *(_Float16*)(smem + X_OFF + b) = (_Float16)fv;
        }
    }
    {
        int e = t >> 2, c = t & 3;
        int b = (c * 128 + e * 2) ^ ((c & 7) << 4);
        *(_Float16*)(smem + SH_OFF + b) = (_Float16)shv;
    }
    __syncthreads();

    // ---- phase C: feat = w*x*sh (pk f16), segment-sum via M-matrix MFMA ----
    const int nseg = *(const int*)(smem + NSEG_OFF);
    const int npass = (nseg + 15) >> 4;
    for (int p = 0; p < npass; ++p) {
        // A = M[seg][edge] (0/1 f16), rows p*16..p*16+16
        h8 afr0, afr1;
        {
            const unsigned tgt = (unsigned)(p * 16 + lr);
#pragma unroll
            for (int ks = 0; ks < 2; ++ks) {
                uint4 sv = *(const uint4*)(smem + SID_OFF + ks * 64 + lk * 16);
                unsigned vv[4] = { sv.x, sv.y, sv.z, sv.w };
                h8 a;
#pragma unroll
                for (int w2 = 0; w2 < 4; ++w2) {
                    a[w2 * 2]     = ((vv[w2] & 0xffffu) == tgt) ? (_Float16)1.f : (_Float16)0.f;
                    a[w2 * 2 + 1] = ((vv[w2] >> 16)     == tgt) ? (_Float16)1.f : (_Float16)0.f;
                }
                if (ks == 0) afr0 = a; else afr1 = a;
            }
        }
        for (int nt = wv * 6; nt < wv * 6 + 6; ++nt) {
            const int f = nt * 16 + lr;
            int wr, xr, shr;
            bool cls_s1 = false;
            if (nt < 4)       { wr = f; xr = f; shr = 0; }
            else if (nt < 6)  { cls_s1 = true; wr = 160 + (f - 64); xr = 0; shr = 0; }
            else if (nt < 18) { int k2 = f - 96;  int u = k2 / 3; wr = 64 + u;  xr = u;       shr = 1 + k2 - 3 * u; }
            else              { int k2 = f - 288;                 wr = 128 + k2 / 3; xr = 64 + k2; shr = 0; }
            f32x4 acc = {0.f, 0.f, 0.f, 0.f};
#pragma unroll
            for (int ks = 0; ks < 2; ++ks) {
                const int eb = ks * 64 + lk * 16;
                h8 w = lds_h8(smem + W_OFF, wr, eb);
                h8 bf;
                if (cls_s1) {
                    int x0r = 64 + 3 * (f - 64);
                    h8 m = lds_h8(smem + X_OFF, x0r,     eb) * lds_h8(smem + SH_OFF, 1, eb)
                         + lds_h8(smem + X_OFF, x0r + 1, eb) * lds_h8(smem + SH_OFF, 2, eb)
                         + lds_h8(smem + X_OFF, x0r + 2, eb) * lds_h8(smem + SH_OFF, 3, eb);
                    bf = w * m;
                } else {
                    bf = w * lds_h8(smem + X_OFF, xr, eb) * lds_h8(smem + SH_OFF, shr, eb);
                }
                acc = __builtin_amdgcn_mfma_f32_16x16x32_f16(ks ? afr1 : afr0, bf, acc, 0, 0, 0);
            }
            float sc = (nt == 4 || nt == 5) ? INV_SQRT3 : 1.f;
#pragma unroll
            for (int q = 0; q < 4; ++q) {
                int seg = p * 16 + lk * 4 + q;
                if (seg < nseg)
                    atomicAdd(accg + (size_t)s_segnode[seg] * FEAT + f, acc[q] * sc);
            }
        }
    }
}

// ---------------- node epilogue (MFMA) ----------------

static __device__ __forceinline__ s16x8 frag_c8(const float* p, float s) {
    float4 u = *(const float4*)p, v = *(const float4*)(p + 4);
    s16x8 a;
    a[0] = f2bf(u.x * s); a[1] = f2bf(u.y * s); a[2] = f2bf(u.z * s); a[3] = f2bf(u.w * s);
    a[4] = f2bf(v.x * s); a[5] = f2bf(v.y * s); a[6] = f2bf(v.z * s); a[7] = f2bf(v.w * s);
    return a;
}
static __device__ __forceinline__ s16x8 frag_s3(const float* p, float s) {
    s16x8 a;
#pragma unroll
    for (int j = 0; j < 8; ++j) a[j] = f2bf(p[j * 3] * s);
    return a;
}

__global__ __launch_bounds__(256) void node_kernel(
    const float* __restrict__ x,
    const float* __restrict__ accg,
    const int*   __restrict__ cnt,
    const unsigned short* __restrict__ wscs_t,
    const unsigned short* __restrict__ wscv_t,
    const unsigned short* __restrict__ wlins_t,
    const unsigned short* __restrict__ wlinv_t,
    const float* __restrict__ w_alpha,
    float* __restrict__ out)
{
    const int t = threadIdx.x;
    const int wv = t >> 6, l = t & 63;
    const int lr = l & 15, lk = l >> 4;
    const int n_base = blockIdx.x * 64 + wv * 16;
    const int nrow = n_base + lr;
    const int nclamp = min(nrow, N_NODES - 1);

    const float* mrow = accg + (size_t)nclamp * FEAT;
    const float* xrow = x + (size_t)nclamp * D_IN;
    const float rinv = 1.f / (float)max(cnt[nclamp], 1);

    s16x8 ax[2], ams[3], axv[3], amv[3][3];
#pragma unroll
    for (int kk = 0; kk < 2; ++kk) ax[kk] = frag_c8(xrow + kk * 32 + lk * 8, 1.f);
#pragma unroll
    for (int kk = 0; kk < 3; ++kk) ams[kk] = frag_c8(mrow + kk * 32 + lk * 8, rinv);
#pragma unroll
    for (int i = 0; i < 3; ++i) axv[i] = frag_s3(xrow + 64 + 3 * (lk * 8) + i, 1.f);
#pragma unroll
    for (int i = 0; i < 3; ++i)
#pragma unroll
        for (int kk = 0; kk < 3; ++kk)
            amv[i][kk] = frag_s3(mrow + 96 + 3 * (kk * 32 + lk * 8) + i, rinv);

    float ap = 0.f;
#pragma unroll
    for (int j = 0; j < 24; ++j) ap += mrow[lk * 24 + j] * rinv * w_alpha[lk * 24 + j];
    ap += __shfl_xor(ap, 16);
    ap += __shfl_xor(ap, 32);
    const float alphav = ap * RSQRT96;

    f32x4 accA[4], accL[4];
#pragma unroll
    for (int nt = 0; nt < 4; ++nt) { accA[nt] = (f32x4){0,0,0,0}; accL[nt] = (f32x4){0,0,0,0}; }
#pragma unroll
    for (int nt = 0; nt < 4; ++nt) {
#pragma unroll
        for (int kk = 0; kk < 2; ++kk) {
            s16x8 b = *(const s16x8*)(wscs_t + (nt * 16 + lr) * 64 + kk * 32 + lk * 8);
            accA[nt] = __builtin_amdgcn_mfma_f32_16x16x32_bf16(ax[kk], b, accA[nt], 0, 0, 0);
        }
#pragma unroll
        for (int kk = 0; kk < 3; ++kk) {
            s16x8 b = *(const s16x8*)(wlins_t + (nt * 16 + lr) * 96 + kk * 32 + lk * 8);
            accL[nt] = __builtin_amdgcn_mfma_f32_16x16x32_bf16(ams[kk], b, accL[nt], 0, 0, 0);
        }
    }
    f32x4 accVs[3][2], accVl[3][2];
#pragma unroll
    for (int i = 0; i < 3; ++i)
#pragma unroll
        for (int nt = 0; nt < 2; ++nt) { accVs[i][nt] = (f32x4){0,0,0,0}; accVl[i][nt] = (f32x4){0,0,0,0}; }
#pragma unroll
    for (int i = 0; i < 3; ++i) {
#pragma unroll
        for (int nt = 0; nt < 2; ++nt) {
            s16x8 b = *(const s16x8*)(wscv_t + (nt * 16 + lr) * 32 + lk * 8);
            accVs[i][nt] = __builtin_amdgcn_mfma_f32_16x16x32_bf16(axv[i], b, accVs[i][nt], 0, 0, 0);
#pragma unroll
            for (int kk = 0; kk < 3; ++kk) {
                s16x8 b2 = *(const s16x8*)(wlinv_t + (nt * 16 + lr) * 96 + kk * 32 + lk * 8);
                accVl[i][nt] = __builtin_amdgcn_mfma_f32_16x16x32_bf16(amv[i][kk], b2, accVl[i][nt], 0, 0, 0);
            }
        }
    }

#pragma unroll
    for (int q = 0; q < 4; ++q) {
        int row = lk * 4 + q;
        float ar = __shfl(alphav, row);
        int n = n_base + row;
        bool ok = (n < N_NODES);
        float* orow = out + (size_t)n * 160;
#pragma unroll
        for (int nt = 0; nt < 4; ++nt) {
            float vout = accA[nt][q] * 0.125f + ar * accL[nt][q] * RSQRT96;
            if (ok) orow[nt * 16 + lr] = vout;
        }
#pragma unroll
        for (int i = 0; i < 3; ++i)
#pragma unroll
            for (int nt = 0; nt < 2; ++nt) {
                float vout = accVs[i][nt][q] * RSQRT32 + ar * accVl[i][nt][q] * RSQRT96;
                if (ok) orow[64 + 3 * (nt * 16 + lr) + i] = vout;
            }
    }
}

// ---------------- launch ----------------

extern "C" void kernel_launch(void* const* d_in, const int* in_sizes, int n_in,
                              void* d_out, int out_size, void* d_ws, size_t ws_size,
                              hipStream_t stream) {
    const float* x        = (const float*)d_in[0];
    const float* es       = (const float*)d_in[1];
    const float* sh       = (const float*)d_in[2];
    const int*   eidx     = (const int*)d_in[3];
    const float* w_fc1    = (const float*)d_in[4];
    const float* w_fc2    = (const float*)d_in[5];
    const float* w_sc_s   = (const float*)d_in[6];
    const float* w_sc_v   = (const float*)d_in[7];
    const float* w_lin_s  = (const float*)d_in[8];
    const float* w_lin_v  = (const float*)d_in[9];
    const float* w_alpha  = (const float*)d_in[10];
    float* out = (float*)d_out;

    float* accg       = (float*)d_ws;                                  // N*384
    int*   cnt        = (int*)(accg + (size_t)N_NODES * FEAT);         // N
    int*   fill       = cnt + N_NODES;                                 // N
    int*   sorted_eid = fill + N_NODES;                                // E
    unsigned short* w1t     = (unsigned short*)(sorted_eid + N_EDGES);
    unsigned short* w2t     = w1t + 64 * 64;
    unsigned short* wscs_t  = w2t + 192 * 64;
    unsigned short* wscv_t  = wscs_t + 64 * 64;
    unsigned short* wlins_t = wscv_t + 32 * 32;
    unsigned short* wlinv_t = wlins_t + 64 * 96;

    (void)hipMemsetAsync(d_ws, 0, ((size_t)N_NODES * FEAT + N_NODES) * 4, stream);
    hipLaunchKernelGGL(hist_kernel, dim3((N_EDGES + 255) / 256), dim3(256), 0, stream,
                       eidx, cnt);
    hipLaunchKernelGGL(scan_kernel, dim3(1), dim3(1024), 0, stream, cnt, fill);
    hipLaunchKernelGGL(scatter_ids_kernel, dim3((N_EDGES + 255) / 256), dim3(256), 0, stream,
                       eidx, fill, sorted_eid);
    hipLaunchKernelGGL(prep_w_kernel, dim3(48), dim3(256), 0, stream,
                       w_fc1, w_fc2, w_sc_s, w_sc_v, w_lin_s, w_lin_v,
                       w1t, w2t, wscs_t, wscv_t, wlins_t, wlinv_t);
    hipLaunchKernelGGL(edge_kernel, dim3(N_EDGES / TILE), dim3(256), 0, stream,
                       x, es, sh, eidx, sorted_eid, w1t, w2t, accg);
    hipLaunchKernelGGL(node_kernel, dim3((N_NODES + 63) / 64), dim3(256), 0, stream,
                       x, accg, cnt, wscs_t, wscv_t, wlins_t, wlinv_t, w_alpha, out);
}